// Round 1
// baseline (162.425 us; speedup 1.0000x reference)
//
#include <hip/hip_runtime.h>
#include <cstdint>
#include <cstddef>

// ---------- types ----------
using bf16x8 = __attribute__((ext_vector_type(8))) short;
using f32x4  = __attribute__((ext_vector_type(4))) float;

#define MFMA16(a, b, c) __builtin_amdgcn_mfma_f32_16x16x32_bf16((a), (b), (c), 0, 0, 0)

__device__ __forceinline__ unsigned short f2bf(float f) {
    unsigned int u = __float_as_uint(f);
    u += 0x7fffu + ((u >> 16) & 1u);   // round-to-nearest-even
    return (unsigned short)(u >> 16);
}
__device__ __forceinline__ float bflo(uint32_t p) { return __uint_as_float(p << 16); }
__device__ __forceinline__ float bfhi(uint32_t p) { return __uint_as_float(p & 0xffff0000u); }

__device__ __forceinline__ void gload_lds16(const void* g, void* l) {
    __builtin_amdgcn_global_load_lds(
        (const __attribute__((address_space(1))) void*)g,
        (__attribute__((address_space(3))) void*)l, 16, 0, 0);
}

// ---------- constants ----------
#define S_LEN 2048
#define NHEAD 16
#define HDIM  64
#define DIM   1024
#define WIN   512
#define BATCH 2
#define MROWS 4096            // B*S

// ---------- kernel 0: rope table ----------
__global__ void rope_table(float* __restrict__ cosT, float* __restrict__ sinT) {
    int t = blockIdx.x * 256 + threadIdx.x;
    if (t >= S_LEN * 32) return;
    int s = t >> 5, f = t & 31;
    float invf = powf(10000.0f, -(float)f / 32.0f);
    float ang = (float)s * invf;
    cosT[t] = cosf(ang);
    sinT[t] = sinf(ang);
}

// ---------- kernel 1: fp32 -> bf16 cast ----------
__global__ void cast_f32_bf16(const float* __restrict__ src, unsigned short* __restrict__ dst, int n) {
    int i = (blockIdx.x * 256 + threadIdx.x) * 4;
    if (i >= n) return;
    float4 v = *(const float4*)(src + i);
    ushort4 o;
    o.x = f2bf(v.x); o.y = f2bf(v.y); o.z = f2bf(v.z); o.w = f2bf(v.w);
    *(ushort4*)(dst + i) = o;
}

// ---------- GEMM: C[m][n] = sum_k A[m][k]*B[n][k] + bias[n] (NT, bf16 in, fp32 acc) ----------
// 128x128 tile, BK=32, 256 threads (4 waves as 2x2), m97-style global_load_lds staging.
template <int OUT_BF16>
__global__ __launch_bounds__(256) void gemm_nt(const unsigned short* __restrict__ A,
                                               const unsigned short* __restrict__ Bw,
                                               const float* __restrict__ bias,
                                               void* __restrict__ Cout, int N, int K) {
    __shared__ short As[128 * 32];
    __shared__ short Bs[128 * 32];
    const int tid = threadIdx.x;
    const int lane = tid & 63, w = tid >> 6;
    const int wr = w >> 1, wc = w & 1, lm = lane & 15, lg = lane >> 4;
    const int row0 = blockIdx.y * 128, col0 = blockIdx.x * 128;

    f32x4 acc[4][4];
#pragma unroll
    for (int m = 0; m < 4; ++m)
#pragma unroll
        for (int n = 0; n < 4; ++n) acc[m][n] = (f32x4){0.f, 0.f, 0.f, 0.f};

    const size_t ldb = (size_t)K * 2;  // bytes per row
    for (int kt = 0; kt < K; kt += 32) {
#pragma unroll
        for (int i = 0; i < 2; ++i) {
            int c = tid + 256 * i;           // 512 chunks of 16B per 8KB tile
            int r = c >> 2, kc = c & 3;
            gload_lds16((const char*)A  + (size_t)(row0 + r) * ldb + (size_t)kt * 2 + kc * 16, &As[c * 8]);
            gload_lds16((const char*)Bw + (size_t)(col0 + r) * ldb + (size_t)kt * 2 + kc * 16, &Bs[c * 8]);
        }
        __syncthreads();   // compiler drains vmcnt before barrier
        bf16x8 af[4], bfr[4];
#pragma unroll
        for (int m = 0; m < 4; ++m) af[m]  = *(const bf16x8*)&As[(wr * 64 + m * 16 + lm) * 32 + lg * 8];
#pragma unroll
        for (int n = 0; n < 4; ++n) bfr[n] = *(const bf16x8*)&Bs[(wc * 64 + n * 16 + lm) * 32 + lg * 8];
#pragma unroll
        for (int m = 0; m < 4; ++m)
#pragma unroll
            for (int n = 0; n < 4; ++n) acc[m][n] = MFMA16(af[m], bfr[n], acc[m][n]);
        __syncthreads();
    }

#pragma unroll
    for (int m = 0; m < 4; ++m) {
        int row = row0 + wr * 64 + m * 16 + lg * 4;
#pragma unroll
        for (int n = 0; n < 4; ++n) {
            int col = col0 + wc * 64 + n * 16 + lm;
            float bv = bias[col];
#pragma unroll
            for (int r = 0; r < 4; ++r) {
                float v = acc[m][n][r] + bv;
                if (OUT_BF16)
                    ((unsigned short*)Cout)[(size_t)(row + r) * N + col] = f2bf(v);
                else
                    ((float*)Cout)[(size_t)(row + r) * N + col] = v;
            }
        }
    }
}

// ---------- kernel 3a: RoPE + pack q,k into [B][H][S][64] bf16 (q pre-scaled) ----------
__global__ void rope_pack(const unsigned short* __restrict__ qkvb,
                          const float* __restrict__ cosT, const float* __restrict__ sinT,
                          unsigned short* __restrict__ qb, unsigned short* __restrict__ kb) {
    int t = blockIdx.x * 256 + threadIdx.x;       // 2M threads
    int p = t & 511, m = t >> 9;                  // m in [0,4096)
    int h = p >> 5, f = p & 31;
    int s = m & (S_LEN - 1), b = m >> 11;
    float c = cosT[s * 32 + f], sn = sinT[s * 32 + f];
    const float SC = 0.125f;                      // HEAD_DIM^-0.5, exact pow2

    uint32_t qp = *(const uint32_t*)&qkvb[m * 3072 + h * 64 + 2 * f];
    float qe = bflo(qp), qo = bfhi(qp);
    float re = (qe * c - qo * sn) * SC, ro = (qe * sn + qo * c) * SC;
    *(uint32_t*)&qb[((b * NHEAD + h) * S_LEN + s) * 64 + 2 * f] =
        (uint32_t)f2bf(re) | ((uint32_t)f2bf(ro) << 16);

    uint32_t kp = *(const uint32_t*)&qkvb[m * 3072 + 1024 + h * 64 + 2 * f];
    float ke = bflo(kp), ko = bfhi(kp);
    float rke = ke * c - ko * sn, rko = ke * sn + ko * c;
    *(uint32_t*)&kb[((b * NHEAD + h) * S_LEN + s) * 64 + 2 * f] =
        (uint32_t)f2bf(rke) | ((uint32_t)f2bf(rko) << 16);
}

// ---------- kernel 3b: V transpose into [B][H][64][S] bf16 ----------
__global__ __launch_bounds__(256) void v_transpose(const unsigned short* __restrict__ qkvb,
                                                   unsigned short* __restrict__ vt) {
    int st = blockIdx.x, bh = blockIdx.y;
    int h = bh & 15, b = bh >> 4;
    __shared__ unsigned short tile[64][72];
    int tid = threadIdx.x;
#pragma unroll
    for (int i = 0; i < 2; ++i) {
        int c = tid + 256 * i;                    // 512 chunks of 8 bf16
        int r = c >> 3, col = (c & 7) * 8;
        int m = b * S_LEN + st * 64 + r;
        *(bf16x8*)&tile[r][col] = *(const bf16x8*)&qkvb[m * 3072 + 2048 + h * 64 + col];
    }
    __syncthreads();
#pragma unroll
    for (int i = 0; i < 2; ++i) {
        int c = tid + 256 * i;
        int d = c >> 3, scol = (c & 7) * 8;
        unsigned short tmp[8];
#pragma unroll
        for (int j = 0; j < 8; ++j) tmp[j] = tile[scol + j][d];
        *(bf16x8*)&vt[(size_t)bh * 64 * S_LEN + (size_t)d * S_LEN + st * 64 + scol] = *(bf16x8*)tmp;
    }
}

// ---------- kernel 4: sliding-window flash attention ----------
// grid (32 qblocks, 32 bh); 4 waves x 16 query rows; K-tiles of 64.
__global__ __launch_bounds__(256) void attn(const unsigned short* __restrict__ qb,
                                            const unsigned short* __restrict__ kb,
                                            const unsigned short* __restrict__ vt,
                                            unsigned short* __restrict__ ao) {
    const int qblk = blockIdx.x, bh = blockIdx.y;
    const int b = bh >> 4, h = bh & 15;
    const int tid = threadIdx.x, w = tid >> 6, lane = tid & 63;
    const int lm = lane & 15, lg = lane >> 4;
    const unsigned short* Qb = qb + (size_t)bh * S_LEN * 64;
    const unsigned short* Kb = kb + (size_t)bh * S_LEN * 64;
    const unsigned short* Vt = vt + (size_t)bh * 64 * S_LEN;
    const int q0 = qblk * 64 + w * 16;

    bf16x8 aq0 = *(const bf16x8*)&Qb[(q0 + lm) * 64 + lg * 8];
    bf16x8 aq1 = *(const bf16x8*)&Qb[(q0 + lm) * 64 + lg * 8 + 32];

    f32x4 o[4];
    float mr[4], lr[4];
#pragma unroll
    for (int n = 0; n < 4; ++n) o[n] = (f32x4){0.f, 0.f, 0.f, 0.f};
#pragma unroll
    for (int r = 0; r < 4; ++r) { mr[r] = -1e30f; lr[r] = 0.f; }

    __shared__ unsigned short Plds[4][16][72];   // per-wave, padded (2-way conflicts only)
    unsigned short(*P)[72] = Plds[w];

    const int t0 = qblk >= 8 ? qblk - 8 : 0;
    for (int kt = t0; kt <= qblk; ++kt) {
        const int kbase = kt * 64;
        f32x4 s[4];
#pragma unroll
        for (int n = 0; n < 4; ++n) {
            bf16x8 bk0 = *(const bf16x8*)&Kb[(kbase + n * 16 + lm) * 64 + lg * 8];
            bf16x8 bk1 = *(const bf16x8*)&Kb[(kbase + n * 16 + lm) * 64 + lg * 8 + 32];
            f32x4 z = (f32x4){0.f, 0.f, 0.f, 0.f};
            z = MFMA16(aq0, bk0, z);
            s[n] = MFMA16(aq1, bk1, z);
        }
        // mask + row max
        float tm[4] = {-3e38f, -3e38f, -3e38f, -3e38f};
#pragma unroll
        for (int n = 0; n < 4; ++n) {
            int kk = kbase + n * 16 + lm;
#pragma unroll
            for (int r = 0; r < 4; ++r) {
                int qq = q0 + lg * 4 + r;
                bool valid = (kk <= qq) && (qq - kk < WIN);
                float sv = valid ? s[n][r] : -1e30f;
                s[n][r] = sv;
                tm[r] = fmaxf(tm[r], sv);
            }
        }
#pragma unroll
        for (int d = 1; d < 16; d <<= 1)
#pragma unroll
            for (int r = 0; r < 4; ++r) tm[r] = fmaxf(tm[r], __shfl_xor(tm[r], d, 64));
        float al[4], rs[4];
#pragma unroll
        for (int r = 0; r < 4; ++r) {
            float mn = fmaxf(mr[r], tm[r]);
            al[r] = __expf(mr[r] - mn);
            mr[r] = mn;
            rs[r] = 0.f;
        }
#pragma unroll
        for (int n = 0; n < 4; ++n)
#pragma unroll
            for (int r = 0; r < 4; ++r) {
                float pv = __expf(s[n][r] - mr[r]);
                s[n][r] = pv;
                rs[r] += pv;
            }
#pragma unroll
        for (int d = 1; d < 16; d <<= 1)
#pragma unroll
            for (int r = 0; r < 4; ++r) rs[r] += __shfl_xor(rs[r], d, 64);
#pragma unroll
        for (int r = 0; r < 4; ++r) lr[r] = lr[r] * al[r] + rs[r];
#pragma unroll
        for (int n = 0; n < 4; ++n)
#pragma unroll
            for (int r = 0; r < 4; ++r) o[n][r] *= al[r];
        // P -> LDS (per-wave region, no barrier needed)
#pragma unroll
        for (int n = 0; n < 4; ++n)
#pragma unroll
            for (int r = 0; r < 4; ++r) P[lg * 4 + r][n * 16 + lm] = f2bf(s[n][r]);
        bf16x8 ap0 = *(const bf16x8*)&P[lm][lg * 8];
        bf16x8 ap1 = *(const bf16x8*)&P[lm][lg * 8 + 32];
#pragma unroll
        for (int n = 0; n < 4; ++n) {
            bf16x8 bv0 = *(const bf16x8*)&Vt[(n * 16 + lm) * S_LEN + kbase + lg * 8];
            bf16x8 bv1 = *(const bf16x8*)&Vt[(n * 16 + lm) * S_LEN + kbase + lg * 8 + 32];
            o[n] = MFMA16(ap0, bv0, o[n]);
            o[n] = MFMA16(ap1, bv1, o[n]);
        }
    }
#pragma unroll
    for (int r = 0; r < 4; ++r) lr[r] = 1.f / lr[r];
#pragma unroll
    for (int n = 0; n < 4; ++n)
#pragma unroll
        for (int r = 0; r < 4; ++r) {
            int row = b * S_LEN + q0 + lg * 4 + r;
            int col = h * 64 + n * 16 + lm;
            ao[(size_t)row * DIM + col] = f2bf(o[n][r] * lr[r]);
        }
}

// ---------- launch ----------
extern "C" void kernel_launch(void* const* d_in, const int* in_sizes, int n_in,
                              void* d_out, int out_size, void* d_ws, size_t ws_size,
                              hipStream_t stream) {
    const float* x      = (const float*)d_in[0];
    const float* qkv_w  = (const float*)d_in[1];
    const float* qkv_b  = (const float*)d_in[2];
    const float* out_w  = (const float*)d_in[3];
    const float* out_b  = (const float*)d_in[4];
    (void)in_sizes; (void)n_in; (void)out_size; (void)ws_size;

    char* ws = (char*)d_ws;
    float*          cosT = (float*)(ws + 0);
    float*          sinT = (float*)(ws + (256 << 10));
    unsigned short* xb   = (unsigned short*)(ws + (512 << 10));
    unsigned short* wqb  = (unsigned short*)(ws + 8912896);
    unsigned short* owb  = (unsigned short*)(ws + 15204352);
    unsigned short* qkvb = (unsigned short*)(ws + 17301504);
    unsigned short* qbuf = (unsigned short*)(ws + 42467328);
    unsigned short* kbuf = (unsigned short*)(ws + 50855936);
    unsigned short* vtb  = (unsigned short*)(ws + 59244544);
    unsigned short* aob  = (unsigned short*)(ws + 67633152);

    rope_table<<<256, 256, 0, stream>>>(cosT, sinT);
    cast_f32_bf16<<<4096, 256, 0, stream>>>(x, xb, MROWS * DIM);
    cast_f32_bf16<<<3072, 256, 0, stream>>>(qkv_w, wqb, 3 * DIM * DIM);
    cast_f32_bf16<<<1024, 256, 0, stream>>>(out_w, owb, DIM * DIM);

    gemm_nt<1><<<dim3(24, 32), 256, 0, stream>>>(xb, wqb, qkv_b, qkvb, 3 * DIM, DIM);

    rope_pack<<<8192, 256, 0, stream>>>(qkvb, cosT, sinT, qbuf, kbuf);
    v_transpose<<<dim3(32, 32), 256, 0, stream>>>(qkvb, vtb);

    attn<<<dim3(32, 32), 256, 0, stream>>>(qbuf, kbuf, vtb, aob);

    gemm_nt<0><<<dim3(8, 32), 256, 0, stream>>>(aob, owb, out_b, d_out, DIM, DIM);
}

// Round 2
// 154.777 us; speedup vs baseline: 1.0494x; 1.0494x over previous
//
#include <hip/hip_runtime.h>
#include <hip/hip_bf16.h>
#include <cstdint>
#include <cstddef>

// ---------- types ----------
using bf16x8 = __attribute__((ext_vector_type(8))) short;
using f32x4  = __attribute__((ext_vector_type(4))) float;

#define MFMA16(a, b, c) __builtin_amdgcn_mfma_f32_16x16x32_bf16((a), (b), (c), 0, 0, 0)

__device__ __forceinline__ unsigned short f2bf(float f) {
    unsigned int u = __float_as_uint(f);
    u += 0x7fffu + ((u >> 16) & 1u);   // round-to-nearest-even
    return (unsigned short)(u >> 16);
}
__device__ __forceinline__ uint32_t pack2bf(float a, float b) {
    __hip_bfloat162 h = __float22bfloat162_rn(float2{a, b});
    return *(uint32_t*)&h;
}
__device__ __forceinline__ float bflo(uint32_t p) { return __uint_as_float(p << 16); }
__device__ __forceinline__ float bfhi(uint32_t p) { return __uint_as_float(p & 0xffff0000u); }

__device__ __forceinline__ void gload_lds16(const void* g, void* l) {
    __builtin_amdgcn_global_load_lds(
        (const __attribute__((address_space(1))) void*)g,
        (__attribute__((address_space(3))) void*)l, 16, 0, 0);
}

// ---------- constants ----------
#define S_LEN 2048
#define NHEAD 16
#define HDIM  64
#define DIM   1024
#define WIN   512
#define BATCH 2
#define MROWS 4096            // B*S

// ---------- kernel 0 (fused prep): rope table + 3 bf16 casts ----------
// t in [0,64K): cos/sin table; then x (1M thr), qkv_w (768K thr), out_w (256K thr), 4 elems each.
__global__ void prep(float* __restrict__ cosT, float* __restrict__ sinT,
                     const float* __restrict__ x, unsigned short* __restrict__ xb,
                     const float* __restrict__ qw, unsigned short* __restrict__ qwb,
                     const float* __restrict__ ow, unsigned short* __restrict__ owb) {
    int t = blockIdx.x * 256 + threadIdx.x;
    if (t < 65536) {
        int s = t >> 5, f = t & 31;
        float invf = powf(10000.0f, -(float)f / 32.0f);
        float ang = (float)s * invf;
        cosT[t] = cosf(ang);
        sinT[t] = sinf(ang);
        return;
    }
    int u = t - 65536;
    const float* src;
    unsigned short* dst;
    int i;
    if (u < 1048576)        { src = x;  dst = xb;  i = u * 4; }
    else if (u < 1835008)   { src = qw; dst = qwb; i = (u - 1048576) * 4; }
    else                    { src = ow; dst = owb; i = (u - 1835008) * 4; }
    float4 v = *(const float4*)(src + i);
    ushort4 o;
    o.x = f2bf(v.x); o.y = f2bf(v.y); o.z = f2bf(v.z); o.w = f2bf(v.w);
    *(ushort4*)(dst + i) = o;
}

// ---------- GEMM: C[m][n] = sum_k A[m][k]*B[n][k] + bias[n] (NT, bf16 in, fp32 acc) ----------
template <int OUT_BF16>
__global__ __launch_bounds__(256) void gemm_nt(const unsigned short* __restrict__ A,
                                               const unsigned short* __restrict__ Bw,
                                               const float* __restrict__ bias,
                                               void* __restrict__ Cout, int N, int K) {
    __shared__ short As[128 * 32];
    __shared__ short Bs[128 * 32];
    const int tid = threadIdx.x;
    const int lane = tid & 63, w = tid >> 6;
    const int wr = w >> 1, wc = w & 1, lm = lane & 15, lg = lane >> 4;
    const int row0 = blockIdx.y * 128, col0 = blockIdx.x * 128;

    f32x4 acc[4][4];
#pragma unroll
    for (int m = 0; m < 4; ++m)
#pragma unroll
        for (int n = 0; n < 4; ++n) acc[m][n] = (f32x4){0.f, 0.f, 0.f, 0.f};

    const size_t ldb = (size_t)K * 2;  // bytes per row
    for (int kt = 0; kt < K; kt += 32) {
#pragma unroll
        for (int i = 0; i < 2; ++i) {
            int c = tid + 256 * i;           // 512 chunks of 16B per 8KB tile
            int r = c >> 2, kc = c & 3;
            gload_lds16((const char*)A  + (size_t)(row0 + r) * ldb + (size_t)kt * 2 + kc * 16, &As[c * 8]);
            gload_lds16((const char*)Bw + (size_t)(col0 + r) * ldb + (size_t)kt * 2 + kc * 16, &Bs[c * 8]);
        }
        __syncthreads();
        bf16x8 af[4], bfr[4];
#pragma unroll
        for (int m = 0; m < 4; ++m) af[m]  = *(const bf16x8*)&As[(wr * 64 + m * 16 + lm) * 32 + lg * 8];
#pragma unroll
        for (int n = 0; n < 4; ++n) bfr[n] = *(const bf16x8*)&Bs[(wc * 64 + n * 16 + lm) * 32 + lg * 8];
#pragma unroll
        for (int m = 0; m < 4; ++m)
#pragma unroll
            for (int n = 0; n < 4; ++n) acc[m][n] = MFMA16(af[m], bfr[n], acc[m][n]);
        __syncthreads();
    }

#pragma unroll
    for (int m = 0; m < 4; ++m) {
        int row = row0 + wr * 64 + m * 16 + lg * 4;
#pragma unroll
        for (int n = 0; n < 4; ++n) {
            int col = col0 + wc * 64 + n * 16 + lm;
            float bv = bias[col];
#pragma unroll
            for (int r = 0; r < 4; ++r) {
                float v = acc[m][n][r] + bv;
                if (OUT_BF16)
                    ((unsigned short*)Cout)[(size_t)(row + r) * N + col] = f2bf(v);
                else
                    ((float*)Cout)[(size_t)(row + r) * N + col] = v;
            }
        }
    }
}

// ---------- RoPE + pack q,k into [B][H][S][64] bf16 (q pre-scaled by HEAD_DIM^-.5) ----------
__global__ void rope_pack(const unsigned short* __restrict__ qkvb,
                          const float* __restrict__ cosT, const float* __restrict__ sinT,
                          unsigned short* __restrict__ qb, unsigned short* __restrict__ kb) {
    int t = blockIdx.x * 256 + threadIdx.x;       // 2M threads
    int p = t & 511, m = t >> 9;                  // m in [0,4096)
    int h = p >> 5, f = p & 31;
    int s = m & (S_LEN - 1), b = m >> 11;
    float c = cosT[s * 32 + f], sn = sinT[s * 32 + f];
    const float SC = 0.125f;

    uint32_t qp = *(const uint32_t*)&qkvb[m * 3072 + h * 64 + 2 * f];
    float qe = bflo(qp), qo = bfhi(qp);
    float re = (qe * c - qo * sn) * SC, ro = (qe * sn + qo * c) * SC;
    *(uint32_t*)&qb[((b * NHEAD + h) * S_LEN + s) * 64 + 2 * f] =
        (uint32_t)f2bf(re) | ((uint32_t)f2bf(ro) << 16);

    uint32_t kp = *(const uint32_t*)&qkvb[m * 3072 + 1024 + h * 64 + 2 * f];
    float ke = bflo(kp), ko = bfhi(kp);
    float rke = ke * c - ko * sn, rko = ke * sn + ko * c;
    *(uint32_t*)&kb[((b * NHEAD + h) * S_LEN + s) * 64 + 2 * f] =
        (uint32_t)f2bf(rke) | ((uint32_t)f2bf(rko) << 16);
}

// ---------- V transpose into [B][H][64][S] bf16 ----------
__global__ __launch_bounds__(256) void v_transpose(const unsigned short* __restrict__ qkvb,
                                                   unsigned short* __restrict__ vt) {
    int st = blockIdx.x, bh = blockIdx.y;
    int h = bh & 15, b = bh >> 4;
    __shared__ unsigned short tile[64][72];
    int tid = threadIdx.x;
#pragma unroll
    for (int i = 0; i < 2; ++i) {
        int c = tid + 256 * i;                    // 512 chunks of 8 bf16
        int r = c >> 3, col = (c & 7) * 8;
        int m = b * S_LEN + st * 64 + r;
        *(bf16x8*)&tile[r][col] = *(const bf16x8*)&qkvb[m * 3072 + 2048 + h * 64 + col];
    }
    __syncthreads();
#pragma unroll
    for (int i = 0; i < 2; ++i) {
        int c = tid + 256 * i;
        int d = c >> 3, scol = (c & 7) * 8;
        unsigned short tmp[8];
#pragma unroll
        for (int j = 0; j < 8; ++j) tmp[j] = tile[scol + j][d];
        *(bf16x8*)&vt[(size_t)bh * 64 * S_LEN + (size_t)d * S_LEN + st * 64 + scol] = *(bf16x8*)tmp;
    }
}

// ---------- sliding-window flash attention (swapped QK^T, no-max softmax, deferred sum) ----------
// grid (32 qblocks, 32 bh); 4 waves x 16 query rows; K-tiles of 64.
__global__ __launch_bounds__(256) void attn(const unsigned short* __restrict__ qb,
                                            const unsigned short* __restrict__ kb,
                                            const unsigned short* __restrict__ vt,
                                            unsigned short* __restrict__ ao) {
    const int qblk = blockIdx.x, bh = blockIdx.y;
    const int b = bh >> 4, h = bh & 15;
    const int tid = threadIdx.x, w = tid >> 6, lane = tid & 63;
    const int lm = lane & 15, lg = lane >> 4;
    const unsigned short* Qb = qb + (size_t)bh * S_LEN * 64;
    const unsigned short* Kb = kb + (size_t)bh * S_LEN * 64;
    const unsigned short* Vt = vt + (size_t)bh * 64 * S_LEN;
    const int q0 = qblk * 64 + w * 16;

    // Q fragment: row q0+lm, k = lg*8.. (used as B-operand in swapped QK^T)
    bf16x8 aq0 = *(const bf16x8*)&Qb[(q0 + lm) * 64 + lg * 8];
    bf16x8 aq1 = *(const bf16x8*)&Qb[(q0 + lm) * 64 + lg * 8 + 32];

    f32x4 o[4];
#pragma unroll
    for (int n = 0; n < 4; ++n) o[n] = (f32x4){0.f, 0.f, 0.f, 0.f};
    float lsum = 0.f;   // per-lane partial row-sum for q = q0+lm

    __shared__ unsigned short Plds[4][16][72];   // per-wave
    unsigned short(*P)[72] = Plds[w];

    const int qq = q0 + lm;
    const int t0 = qblk >= 8 ? qblk - 8 : 0;
    for (int kt = t0; kt <= qblk; ++kt) {
        const int kbase = kt * 64;
        f32x4 sT[4];
        // S^T = K · Q^T : lane holds q = q0+lm, k = kbase + n*16 + lg*4 + r
#pragma unroll
        for (int n = 0; n < 4; ++n) {
            bf16x8 bk0 = *(const bf16x8*)&Kb[(kbase + n * 16 + lm) * 64 + lg * 8];
            bf16x8 bk1 = *(const bf16x8*)&Kb[(kbase + n * 16 + lm) * 64 + lg * 8 + 32];
            f32x4 z = (f32x4){0.f, 0.f, 0.f, 0.f};
            z = MFMA16(bk0, aq0, z);
            sT[n] = MFMA16(bk1, aq1, z);
        }
        // mask + exp (no max subtraction: scores bounded, exp(-1e30)=0) + deferred sum
#pragma unroll
        for (int n = 0; n < 4; ++n) {
            int kk0 = kbase + n * 16 + lg * 4;
#pragma unroll
            for (int r = 0; r < 4; ++r) {
                int d = qq - (kk0 + r);
                float sv = ((unsigned)d < (unsigned)WIN) ? sT[n][r] : -1e30f;
                float pv = __expf(sv);
                sT[n][r] = pv;
                lsum += pv;
            }
            // P[q=lm][k_local = n*16+lg*4 .. +3]  (one b64 store)
            uint2 pk;
            pk.x = pack2bf(sT[n][0], sT[n][1]);
            pk.y = pack2bf(sT[n][2], sT[n][3]);
            *(uint2*)&P[lm][n * 16 + lg * 4] = pk;
        }
        bf16x8 ap0 = *(const bf16x8*)&P[lm][lg * 8];
        bf16x8 ap1 = *(const bf16x8*)&P[lm][lg * 8 + 32];
#pragma unroll
        for (int n = 0; n < 4; ++n) {
            bf16x8 bv0 = *(const bf16x8*)&Vt[(n * 16 + lm) * S_LEN + kbase + lg * 8];
            bf16x8 bv1 = *(const bf16x8*)&Vt[(n * 16 + lm) * S_LEN + kbase + lg * 8 + 32];
            o[n] = MFMA16(ap0, bv0, o[n]);
            o[n] = MFMA16(ap1, bv1, o[n]);
        }
    }
    // finalize: reduce lsum across the 4 lg-groups (lanes sharing lm), then redistribute
    lsum += __shfl_xor(lsum, 16, 64);
    lsum += __shfl_xor(lsum, 32, 64);
    float linv = 1.f / lsum;           // for q = q0+lm, all lg
    float lrow[4];
#pragma unroll
    for (int r = 0; r < 4; ++r) lrow[r] = __shfl(linv, lg * 4 + r, 64);   // lane lg*4+r has lm=lg*4+r
#pragma unroll
    for (int n = 0; n < 4; ++n)
#pragma unroll
        for (int r = 0; r < 4; ++r) {
            int row = b * S_LEN + q0 + lg * 4 + r;
            int col = h * 64 + n * 16 + lm;
            ao[(size_t)row * DIM + col] = f2bf(o[n][r] * lrow[r]);
        }
}

// ---------- launch ----------
extern "C" void kernel_launch(void* const* d_in, const int* in_sizes, int n_in,
                              void* d_out, int out_size, void* d_ws, size_t ws_size,
                              hipStream_t stream) {
    const float* x      = (const float*)d_in[0];
    const float* qkv_w  = (const float*)d_in[1];
    const float* qkv_b  = (const float*)d_in[2];
    const float* out_w  = (const float*)d_in[3];
    const float* out_b  = (const float*)d_in[4];
    (void)in_sizes; (void)n_in; (void)out_size; (void)ws_size;

    char* ws = (char*)d_ws;
    float*          cosT = (float*)(ws + 0);
    float*          sinT = (float*)(ws + (256 << 10));
    unsigned short* xb   = (unsigned short*)(ws + (512 << 10));
    unsigned short* wqb  = (unsigned short*)(ws + 8912896);
    unsigned short* owb  = (unsigned short*)(ws + 15204352);
    unsigned short* qkvb = (unsigned short*)(ws + 17301504);
    unsigned short* qbuf = (unsigned short*)(ws + 42467328);
    unsigned short* kbuf = (unsigned short*)(ws + 50855936);
    unsigned short* vtb  = (unsigned short*)(ws + 59244544);
    unsigned short* aob  = (unsigned short*)(ws + 67633152);

    prep<<<8448, 256, 0, stream>>>(cosT, sinT, x, xb, qkv_w, wqb, out_w, owb);

    gemm_nt<1><<<dim3(24, 32), 256, 0, stream>>>(xb, wqb, qkv_b, qkvb, 3 * DIM, DIM);

    rope_pack<<<8192, 256, 0, stream>>>(qkvb, cosT, sinT, qbuf, kbuf);
    v_transpose<<<dim3(32, 32), 256, 0, stream>>>(qkvb, vtb);

    attn<<<dim3(32, 32), 256, 0, stream>>>(qbuf, kbuf, vtb, aob);

    gemm_nt<0><<<dim3(8, 32), 256, 0, stream>>>(aob, owb, out_b, d_out, DIM, DIM);
}

// Round 3
// 111.410 us; speedup vs baseline: 1.4579x; 1.3893x over previous
//
#include <hip/hip_runtime.h>
#include <hip/hip_bf16.h>
#include <cstdint>
#include <cstddef>

// ---------- types ----------
using bf16x8 = __attribute__((ext_vector_type(8))) short;
using f32x4  = __attribute__((ext_vector_type(4))) float;

#define MFMA16(a, b, c) __builtin_amdgcn_mfma_f32_16x16x32_bf16((a), (b), (c), 0, 0, 0)

__device__ __forceinline__ unsigned short f2bf(float f) {
    unsigned int u = __float_as_uint(f);
    u += 0x7fffu + ((u >> 16) & 1u);   // round-to-nearest-even
    return (unsigned short)(u >> 16);
}
__device__ __forceinline__ uint32_t pack2bf(float a, float b) {
    __hip_bfloat162 h = __float22bfloat162_rn(float2{a, b});
    return *(uint32_t*)&h;
}
__device__ __forceinline__ float bflo(uint32_t p) { return __uint_as_float(p << 16); }
__device__ __forceinline__ float bfhi(uint32_t p) { return __uint_as_float(p & 0xffff0000u); }

__device__ __forceinline__ void gload_lds16(const void* g, void* l) {
    __builtin_amdgcn_global_load_lds(
        (const __attribute__((address_space(1))) void*)g,
        (__attribute__((address_space(3))) void*)l, 16, 0, 0);
}

// ---------- constants ----------
#define S_LEN 2048
#define NHEAD 16
#define HDIM  64
#define DIM   1024
#define WIN   512
#define BATCH 2
#define MROWS 4096            // B*S

// ---------- kernel 0 (fused prep): rope table + 3 bf16 casts ----------
__global__ void prep(float* __restrict__ cosT, float* __restrict__ sinT,
                     const float* __restrict__ x, unsigned short* __restrict__ xb,
                     const float* __restrict__ qw, unsigned short* __restrict__ qwb,
                     const float* __restrict__ ow, unsigned short* __restrict__ owb) {
    int t = blockIdx.x * 256 + threadIdx.x;
    if (t < 65536) {
        int s = t >> 5, f = t & 31;
        float invf = powf(10000.0f, -(float)f / 32.0f);
        float ang = (float)s * invf;
        cosT[t] = cosf(ang);
        sinT[t] = sinf(ang);
        return;
    }
    int u = t - 65536;
    const float* src;
    unsigned short* dst;
    int i;
    if (u < 1048576)        { src = x;  dst = xb;  i = u * 4; }
    else if (u < 1835008)   { src = qw; dst = qwb; i = (u - 1048576) * 4; }
    else                    { src = ow; dst = owb; i = (u - 1835008) * 4; }
    float4 v = *(const float4*)(src + i);
    ushort4 o;
    o.x = f2bf(v.x); o.y = f2bf(v.y); o.z = f2bf(v.z); o.w = f2bf(v.w);
    *(ushort4*)(dst + i) = o;
}

// ---------- GEMM: C[m][n] = sum_k A[m][k]*B[n][k] + bias[n] (NT, bf16 in, fp32 acc) ----------
template <int OUT_BF16>
__global__ __launch_bounds__(256) void gemm_nt(const unsigned short* __restrict__ A,
                                               const unsigned short* __restrict__ Bw,
                                               const float* __restrict__ bias,
                                               void* __restrict__ Cout, int N, int K) {
    __shared__ short As[128 * 32];
    __shared__ short Bs[128 * 32];
    const int tid = threadIdx.x;
    const int lane = tid & 63, w = tid >> 6;
    const int wr = w >> 1, wc = w & 1, lm = lane & 15, lg = lane >> 4;
    const int row0 = blockIdx.y * 128, col0 = blockIdx.x * 128;

    f32x4 acc[4][4];
#pragma unroll
    for (int m = 0; m < 4; ++m)
#pragma unroll
        for (int n = 0; n < 4; ++n) acc[m][n] = (f32x4){0.f, 0.f, 0.f, 0.f};

    const size_t ldb = (size_t)K * 2;  // bytes per row
    for (int kt = 0; kt < K; kt += 32) {
#pragma unroll
        for (int i = 0; i < 2; ++i) {
            int c = tid + 256 * i;           // 512 chunks of 16B per 8KB tile
            int r = c >> 2, kc = c & 3;
            gload_lds16((const char*)A  + (size_t)(row0 + r) * ldb + (size_t)kt * 2 + kc * 16, &As[c * 8]);
            gload_lds16((const char*)Bw + (size_t)(col0 + r) * ldb + (size_t)kt * 2 + kc * 16, &Bs[c * 8]);
        }
        __syncthreads();
        bf16x8 af[4], bfr[4];
#pragma unroll
        for (int m = 0; m < 4; ++m) af[m]  = *(const bf16x8*)&As[(wr * 64 + m * 16 + lm) * 32 + lg * 8];
#pragma unroll
        for (int n = 0; n < 4; ++n) bfr[n] = *(const bf16x8*)&Bs[(wc * 64 + n * 16 + lm) * 32 + lg * 8];
#pragma unroll
        for (int m = 0; m < 4; ++m)
#pragma unroll
            for (int n = 0; n < 4; ++n) acc[m][n] = MFMA16(af[m], bfr[n], acc[m][n]);
        __syncthreads();
    }

#pragma unroll
    for (int m = 0; m < 4; ++m) {
        int row = row0 + wr * 64 + m * 16 + lg * 4;
#pragma unroll
        for (int n = 0; n < 4; ++n) {
            int col = col0 + wc * 64 + n * 16 + lm;
            float bv = bias[col];
#pragma unroll
            for (int r = 0; r < 4; ++r) {
                float v = acc[m][n][r] + bv;
                if (OUT_BF16)
                    ((unsigned short*)Cout)[(size_t)(row + r) * N + col] = f2bf(v);
                else
                    ((float*)Cout)[(size_t)(row + r) * N + col] = v;
            }
        }
    }
}

// ---------- RoPE + pack q,k into [B][H][S][64] bf16 (q pre-scaled by HEAD_DIM^-.5) ----------
__global__ void rope_pack(const unsigned short* __restrict__ qkvb,
                          const float* __restrict__ cosT, const float* __restrict__ sinT,
                          unsigned short* __restrict__ qb, unsigned short* __restrict__ kb) {
    int t = blockIdx.x * 256 + threadIdx.x;       // 2M threads
    int p = t & 511, m = t >> 9;                  // m in [0,4096)
    int h = p >> 5, f = p & 31;
    int s = m & (S_LEN - 1), b = m >> 11;
    float c = cosT[s * 32 + f], sn = sinT[s * 32 + f];
    const float SC = 0.125f;

    uint32_t qp = *(const uint32_t*)&qkvb[m * 3072 + h * 64 + 2 * f];
    float qe = bflo(qp), qo = bfhi(qp);
    float re = (qe * c - qo * sn) * SC, ro = (qe * sn + qo * c) * SC;
    *(uint32_t*)&qb[((b * NHEAD + h) * S_LEN + s) * 64 + 2 * f] =
        (uint32_t)f2bf(re) | ((uint32_t)f2bf(ro) << 16);

    uint32_t kp = *(const uint32_t*)&qkvb[m * 3072 + 1024 + h * 64 + 2 * f];
    float ke = bflo(kp), ko = bfhi(kp);
    float rke = ke * c - ko * sn, rko = ke * sn + ko * c;
    *(uint32_t*)&kb[((b * NHEAD + h) * S_LEN + s) * 64 + 2 * f] =
        (uint32_t)f2bf(rke) | ((uint32_t)f2bf(rko) << 16);
}

// ---------- V transpose into [B][H][64][S] bf16 ----------
__global__ __launch_bounds__(256) void v_transpose(const unsigned short* __restrict__ qkvb,
                                                   unsigned short* __restrict__ vt) {
    int st = blockIdx.x, bh = blockIdx.y;
    int h = bh & 15, b = bh >> 4;
    __shared__ unsigned short tile[64][72];
    int tid = threadIdx.x;
#pragma unroll
    for (int i = 0; i < 2; ++i) {
        int c = tid + 256 * i;                    // 512 chunks of 8 bf16
        int r = c >> 3, col = (c & 7) * 8;
        int m = b * S_LEN + st * 64 + r;
        *(bf16x8*)&tile[r][col] = *(const bf16x8*)&qkvb[m * 3072 + 2048 + h * 64 + col];
    }
    __syncthreads();
#pragma unroll
    for (int i = 0; i < 2; ++i) {
        int c = tid + 256 * i;
        int d = c >> 3, scol = (c & 7) * 8;
        unsigned short tmp[8];
#pragma unroll
        for (int j = 0; j < 8; ++j) tmp[j] = tile[scol + j][d];
        *(bf16x8*)&vt[(size_t)bh * 64 * S_LEN + (size_t)d * S_LEN + st * 64 + scol] = *(bf16x8*)tmp;
    }
}

// ---------- sliding-window flash attention v3 ----------
// LDS-staged K/V (double-buffered, global_load_lds, XOR-swizzled), XCD-chunked blocks,
// swapped QK^T, no-max softmax, deferred row-sum. 1024 blocks x 4 waves; LDS = 40KB -> 4 blk/CU.
__global__ __launch_bounds__(256) void attn(const unsigned short* __restrict__ qb,
                                            const unsigned short* __restrict__ kb,
                                            const unsigned short* __restrict__ vt,
                                            unsigned short* __restrict__ ao) {
    // XCD-chunk remap: physical p -> logical L so each XCD owns 4 consecutive bh (K/V L2-resident)
    const int p = blockIdx.x;
    const int L = (p & 7) * 128 + (p >> 3);
    const int qblk = L & 31, bh = L >> 5;
    const int b = bh >> 4, h = bh & 15;
    const int tid = threadIdx.x, w = tid >> 6, lane = tid & 63;
    const int lm = lane & 15, lg = lane >> 4;
    const unsigned short* Qb = qb + (size_t)bh * S_LEN * 64;
    const unsigned short* Kb = kb + (size_t)bh * S_LEN * 64;
    const unsigned short* Vt = vt + (size_t)bh * 64 * S_LEN;
    const int q0 = qblk * 64 + w * 16;

    __shared__ short Ks[2][64 * 64];     // 16KB  (granule-swizzled rows)
    __shared__ short Vs[2][64 * 64];     // 16KB  (V^T tile, granule-swizzled rows)
    __shared__ short Plds[4][16 * 64];   // 8KB   (per-wave, granule-swizzled)
    short* Pw = Plds[w];

    // Q fragment (B-operand of swapped QK^T): row q0+lm, hd = lg*8..
    bf16x8 aq0 = *(const bf16x8*)&Qb[(q0 + lm) * 64 + lg * 8];
    bf16x8 aq1 = *(const bf16x8*)&Qb[(q0 + lm) * 64 + lg * 8 + 32];

    f32x4 o[4];
#pragma unroll
    for (int n = 0; n < 4; ++n) o[n] = (f32x4){0.f, 0.f, 0.f, 0.f};
    float lsum = 0.f;   // per-lane partial row-sum for q = q0+lm

    const int qq = q0 + lm;
    const int t0 = qblk >= 8 ? qblk - 8 : 0;

    // stage tile kt into buf: linear LDS dest, inverse-swizzled global source (rule 21)
    auto stage = [&](int kt, int buf) {
#pragma unroll
        for (int i = 0; i < 2; ++i) {
            int c = tid + 256 * i;                 // 512 granules of 16B per tile
            int r = c >> 3, g = (c & 7) ^ (r & 7); // row, swizzled granule
            gload_lds16(Kb + (size_t)(kt * 64 + r) * 64 + g * 8, &Ks[buf][c * 8]);
            gload_lds16(Vt + (size_t)r * S_LEN + kt * 64 + g * 8, &Vs[buf][c * 8]);
        }
    };

    stage(t0, 0);
    __syncthreads();
    int cur = 0;
    for (int kt = t0; kt <= qblk; ++kt) {
        if (kt < qblk) stage(kt + 1, cur ^ 1);
        const int kbase = kt * 64;
        const int sw = lm & 7;                      // row&7 for all our rows (row%16==lm)
        f32x4 sT[4];
        // S^T = K·Q^T : lane holds q=q0+lm, k = kbase + n*16 + lg*4 + r
#pragma unroll
        for (int n = 0; n < 4; ++n) {
            int rl = n * 16 + lm;
            bf16x8 bk0 = *(const bf16x8*)&Ks[cur][rl * 64 + ((lg ^ sw) << 3)];
            bf16x8 bk1 = *(const bf16x8*)&Ks[cur][rl * 64 + (((lg + 4) ^ sw) << 3)];
            f32x4 z = (f32x4){0.f, 0.f, 0.f, 0.f};
            z = MFMA16(bk0, aq0, z);
            sT[n] = MFMA16(bk1, aq1, z);
        }
        // mask + exp (no max subtraction; exp(-1e30)=0) + deferred sum + P store
#pragma unroll
        for (int n = 0; n < 4; ++n) {
            int kk0 = kbase + n * 16 + lg * 4;
#pragma unroll
            for (int r = 0; r < 4; ++r) {
                int d = qq - (kk0 + r);
                float sv = ((unsigned)d < (unsigned)WIN) ? sT[n][r] : -1e30f;
                float pv = __expf(sv);
                sT[n][r] = pv;
                lsum += pv;
            }
            uint2 pk;
            pk.x = pack2bf(sT[n][0], sT[n][1]);
            pk.y = pack2bf(sT[n][2], sT[n][3]);
            // P[q=lm][kloc=16n+4lg..+3]: granule (2n+lg/2)^(lm&7), 8B half lg&1
            *(uint2*)&Pw[lm * 64 + ((((2 * n + (lg >> 1)) ^ sw) << 3) + ((lg & 1) << 2))] = pk;
        }
        bf16x8 ap0 = *(const bf16x8*)&Pw[lm * 64 + ((lg ^ sw) << 3)];
        bf16x8 ap1 = *(const bf16x8*)&Pw[lm * 64 + (((lg + 4) ^ sw) << 3)];
#pragma unroll
        for (int n = 0; n < 4; ++n) {
            int rl = n * 16 + lm;                   // d-row of V^T tile
            bf16x8 bv0 = *(const bf16x8*)&Vs[cur][rl * 64 + ((lg ^ sw) << 3)];
            bf16x8 bv1 = *(const bf16x8*)&Vs[cur][rl * 64 + (((lg + 4) ^ sw) << 3)];
            o[n] = MFMA16(ap0, bv0, o[n]);
            o[n] = MFMA16(ap1, bv1, o[n]);
        }
        __syncthreads();   // next tile staged; all waves done with cur
        cur ^= 1;
    }
    // reduce lsum across lg-groups (lanes sharing lm), then redistribute to output rows
    lsum += __shfl_xor(lsum, 16, 64);
    lsum += __shfl_xor(lsum, 32, 64);
    float linv = 1.f / lsum;
    float lrow[4];
#pragma unroll
    for (int r = 0; r < 4; ++r) lrow[r] = __shfl(linv, lg * 4 + r, 64);
#pragma unroll
    for (int n = 0; n < 4; ++n)
#pragma unroll
        for (int r = 0; r < 4; ++r) {
            int row = b * S_LEN + q0 + lg * 4 + r;
            int col = h * 64 + n * 16 + lm;
            ao[(size_t)row * DIM + col] = f2bf(o[n][r] * lrow[r]);
        }
}

// ---------- launch ----------
extern "C" void kernel_launch(void* const* d_in, const int* in_sizes, int n_in,
                              void* d_out, int out_size, void* d_ws, size_t ws_size,
                              hipStream_t stream) {
    const float* x      = (const float*)d_in[0];
    const float* qkv_w  = (const float*)d_in[1];
    const float* qkv_b  = (const float*)d_in[2];
    const float* out_w  = (const float*)d_in[3];
    const float* out_b  = (const float*)d_in[4];
    (void)in_sizes; (void)n_in; (void)out_size; (void)ws_size;

    char* ws = (char*)d_ws;
    float*          cosT = (float*)(ws + 0);
    float*          sinT = (float*)(ws + (256 << 10));
    unsigned short* xb   = (unsigned short*)(ws + (512 << 10));
    unsigned short* wqb  = (unsigned short*)(ws + 8912896);
    unsigned short* owb  = (unsigned short*)(ws + 15204352);
    unsigned short* qkvb = (unsigned short*)(ws + 17301504);
    unsigned short* qbuf = (unsigned short*)(ws + 42467328);
    unsigned short* kbuf = (unsigned short*)(ws + 50855936);
    unsigned short* vtb  = (unsigned short*)(ws + 59244544);
    unsigned short* aob  = (unsigned short*)(ws + 67633152);

    prep<<<8448, 256, 0, stream>>>(cosT, sinT, x, xb, qkv_w, wqb, out_w, owb);

    gemm_nt<1><<<dim3(24, 32), 256, 0, stream>>>(xb, wqb, qkv_b, qkvb, 3 * DIM, DIM);

    rope_pack<<<8192, 256, 0, stream>>>(qkvb, cosT, sinT, qbuf, kbuf);
    v_transpose<<<dim3(32, 32), 256, 0, stream>>>(qkvb, vtb);

    attn<<<1024, 256, 0, stream>>>(qbuf, kbuf, vtb, aob);

    gemm_nt<0><<<dim3(8, 32), 256, 0, stream>>>(aob, owb, out_b, d_out, DIM, DIM);
}

// Round 5
// 104.978 us; speedup vs baseline: 1.5472x; 1.0613x over previous
//
#include <hip/hip_runtime.h>
#include <hip/hip_bf16.h>
#include <cstdint>
#include <cstddef>

// ---------- types ----------
using bf16x8 = __attribute__((ext_vector_type(8))) short;
using f32x4  = __attribute__((ext_vector_type(4))) float;

#define MFMA16(a, b, c) __builtin_amdgcn_mfma_f32_16x16x32_bf16((a), (b), (c), 0, 0, 0)

__device__ __forceinline__ unsigned short f2bf(float f) {
    unsigned int u = __float_as_uint(f);
    u += 0x7fffu + ((u >> 16) & 1u);   // round-to-nearest-even
    return (unsigned short)(u >> 16);
}
__device__ __forceinline__ uint32_t pack2bf(float a, float b) {
    __hip_bfloat162 h = __float22bfloat162_rn(float2{a, b});
    return *(uint32_t*)&h;
}
__device__ __forceinline__ float bf2f(short x) {
    return __uint_as_float(((uint32_t)(unsigned short)x) << 16);
}
__device__ __forceinline__ float bflo(uint32_t p) { return __uint_as_float(p << 16); }
__device__ __forceinline__ float bfhi(uint32_t p) { return __uint_as_float(p & 0xffff0000u); }

__device__ __forceinline__ void gload_lds16(const void* g, void* l) {
    __builtin_amdgcn_global_load_lds(
        (const __attribute__((address_space(1))) void*)g,
        (__attribute__((address_space(3))) void*)l, 16, 0, 0);
}

// ---------- constants ----------
#define S_LEN 2048
#define NHEAD 16
#define HDIM  64
#define DIM   1024
#define WIN   512
#define MROWS 4096            // B*S

// ---------- kernel 0 (fused prep): rope table + 3 bf16 casts ----------
__global__ void prep(float* __restrict__ cosT, float* __restrict__ sinT,
                     const float* __restrict__ x, unsigned short* __restrict__ xb,
                     const float* __restrict__ qw, unsigned short* __restrict__ qwb,
                     const float* __restrict__ ow, unsigned short* __restrict__ owb) {
    int t = blockIdx.x * 256 + threadIdx.x;
    if (t < 65536) {
        int s = t >> 5, f = t & 31;
        float invf = powf(10000.0f, -(float)f / 32.0f);
        float ang = (float)s * invf;
        cosT[t] = cosf(ang);
        sinT[t] = sinf(ang);
        return;
    }
    int u = t - 65536;
    const float* src;
    unsigned short* dst;
    int i;
    if (u < 1048576)        { src = x;  dst = xb;  i = u * 4; }
    else if (u < 1835008)   { src = qw; dst = qwb; i = (u - 1048576) * 4; }
    else                    { src = ow; dst = owb; i = (u - 1835008) * 4; }
    float4 v = *(const float4*)(src + i);
    ushort4 o;
    o.x = f2bf(v.x); o.y = f2bf(v.y); o.z = f2bf(v.z); o.w = f2bf(v.w);
    *(ushort4*)(dst + i) = o;
}

// ======================================================================
// Shared GEMM main-loop pattern: 128x128 tile, BK=32, 4 waves (2x2),
// double-buffered LDS + prefetch (T3-minimum), granule XOR-swizzle
// (g ^ ((row>>1)&3)) applied to global source + ds_read (rule 21).
// ======================================================================

// ---------- fused QKV GEMM: C = x@W^T + b, then RoPE/pack/V-transpose epilogue ----------
__global__ __launch_bounds__(256) void gemm_qkv_fused(
        const unsigned short* __restrict__ A,    // xb   [4096][1024]
        const unsigned short* __restrict__ Bw,   // wqb  [3072][1024]
        const float* __restrict__ bias,          // qkv_b[3072]
        const float* __restrict__ cosT, const float* __restrict__ sinT,
        unsigned short* __restrict__ qbuf,       // [32][2048][64]
        unsigned short* __restrict__ kbuf,       // [32][2048][64]
        unsigned short* __restrict__ vtb) {      // [32][64][2048]
    __shared__ __align__(16) char smem_raw[32768];   // 2 bufs x (A 8KB + B 8KB)
    const int tid = threadIdx.x;
    const int lane = tid & 63, w = tid >> 6;
    const int wr = w >> 1, wc = w & 1, lm = lane & 15, lg = lane >> 4;
    const int bx = blockIdx.x, by = blockIdx.y;
    const int row0 = by * 128, col0 = bx * 128;
    const int plane = bx >> 3;                 // 0=Q 1=K 2=V
    const int h0 = (bx & 7) * 2;
    const int b = by >> 4, s_base = (by & 15) * 128;

    f32x4 acc[4][4];
#pragma unroll
    for (int m = 0; m < 4; ++m)
#pragma unroll
        for (int n = 0; n < 4; ++n) acc[m][n] = (f32x4){0.f, 0.f, 0.f, 0.f};

    auto As = [&](int buf) { return (short*)(smem_raw + buf * 16384); };
    auto Bs = [&](int buf) { return (short*)(smem_raw + buf * 16384 + 8192); };

    const size_t ldb = 2048;                   // K=1024 rows, bytes
    auto stage = [&](int kt, int buf) {
#pragma unroll
        for (int i = 0; i < 2; ++i) {
            int c = tid + 256 * i;             // 512 x 16B per 8KB tile
            int r = c >> 2, gp = c & 3;
            int gs = gp ^ ((r >> 1) & 3);      // inverse-swizzled source granule
            gload_lds16((const char*)A  + (size_t)(row0 + r) * ldb + (size_t)kt * 64 + gs * 16, As(buf) + c * 8);
            gload_lds16((const char*)Bw + (size_t)(col0 + r) * ldb + (size_t)kt * 64 + gs * 16, Bs(buf) + c * 8);
        }
    };

    stage(0, 0);
    __syncthreads();
    int cur = 0;
    const int swz = (lm >> 1) & 3;             // rows are 16-aligned + lm
    for (int kt = 0; kt < 32; ++kt) {
        if (kt + 1 < 32) stage(kt + 1, cur ^ 1);
        bf16x8 af[4], bfr[4];
        const short* as = As(cur);
        const short* bs = Bs(cur);
#pragma unroll
        for (int m = 0; m < 4; ++m) af[m]  = *(const bf16x8*)&as[(wr * 64 + m * 16 + lm) * 32 + ((lg ^ swz) << 3)];
#pragma unroll
        for (int n = 0; n < 4; ++n) bfr[n] = *(const bf16x8*)&bs[(wc * 64 + n * 16 + lm) * 32 + ((lg ^ swz) << 3)];
#pragma unroll
        for (int m = 0; m < 4; ++m)
#pragma unroll
            for (int n = 0; n < 4; ++n) acc[m][n] = MFMA16(af[m], bfr[n], acc[m][n]);
        __syncthreads();
        cur ^= 1;
    }

    // ---------- fused epilogue: bias + (RoPE pack | V transpose), LDS retile ----------
    unsigned short (*tile)[136] = (unsigned short(*)[136])smem_raw;  // Q/K: [64][128+8]
    unsigned short (*tileT)[72] = (unsigned short(*)[72])smem_raw;   // V:   [128][64+8]
    const int lane8 = tid & 7, idx = tid >> 3;

#pragma unroll 1
    for (int half = 0; half < 2; ++half) {
        __syncthreads();
        if (wr == half) {
            if (plane < 2) {
#pragma unroll
                for (int m = 0; m < 4; ++m)
#pragma unroll
                    for (int n = 0; n < 4; ++n) {
                        int colL = wc * 64 + n * 16 + lm;
                        float bv = bias[col0 + colL];
#pragma unroll
                        for (int r = 0; r < 4; ++r)
                            tile[m * 16 + lg * 4 + r][colL] = f2bf(acc[m][n][r] + bv);
                    }
            } else {
#pragma unroll
                for (int m = 0; m < 4; ++m)
#pragma unroll
                    for (int n = 0; n < 4; ++n) {
                        int colL = wc * 64 + n * 16 + lm;
                        float bv = bias[col0 + colL];
                        uint2 pk;
                        pk.x = pack2bf(acc[m][n][0] + bv, acc[m][n][1] + bv);
                        pk.y = pack2bf(acc[m][n][2] + bv, acc[m][n][3] + bv);
                        *(uint2*)&tileT[colL][m * 16 + lg * 4] = pk;
                    }
            }
        }
        __syncthreads();
        if (plane < 2) {
            unsigned short* dstp = (plane == 0) ? qbuf : kbuf;
            const float qsc = (plane == 0) ? 0.125f : 1.0f;
            int d0 = lane8 * 8;
#pragma unroll
            for (int j = 0; j < 2; ++j) {
                int srow = idx + 32 * j;                     // 0..63
                int s = s_base + half * 64 + srow;
                float4 c4 = *(const float4*)&cosT[s * 32 + (d0 >> 1)];
                float4 s4 = *(const float4*)&sinT[s * 32 + (d0 >> 1)];
#pragma unroll
                for (int hh = 0; hh < 2; ++hh) {
                    bf16x8 v = *(const bf16x8*)&tile[srow][hh * 64 + d0];
                    float e0 = bf2f(v[0]), o0 = bf2f(v[1]);
                    float e1 = bf2f(v[2]), o1 = bf2f(v[3]);
                    float e2 = bf2f(v[4]), o2 = bf2f(v[5]);
                    float e3 = bf2f(v[6]), o3 = bf2f(v[7]);
                    uint4 pk;
                    pk.x = pack2bf((e0 * c4.x - o0 * s4.x) * qsc, (e0 * s4.x + o0 * c4.x) * qsc);
                    pk.y = pack2bf((e1 * c4.y - o1 * s4.y) * qsc, (e1 * s4.y + o1 * c4.y) * qsc);
                    pk.z = pack2bf((e2 * c4.z - o2 * s4.z) * qsc, (e2 * s4.z + o2 * c4.z) * qsc);
                    pk.w = pack2bf((e3 * c4.w - o3 * s4.w) * qsc, (e3 * s4.w + o3 * c4.w) * qsc);
                    int h = h0 + hh;
                    *(uint4*)&dstp[(((size_t)(b * NHEAD + h)) * S_LEN + s) * 64 + d0] = pk;
                }
            }
        } else {
#pragma unroll
            for (int rr = 0; rr < 4; ++rr) {
                int hd = rr * 32 + idx;                      // 0..127
                int hh = hd >> 6, d = hd & 63, h = h0 + hh;
                bf16x8 v = *(const bf16x8*)&tileT[hd][lane8 * 8];
                *(bf16x8*)&vtb[((size_t)(b * NHEAD + h) * 64 + d) * S_LEN +
                               s_base + half * 64 + lane8 * 8] = v;
            }
        }
    }
}

// ---------- out-proj GEMM: fp32 out, improved main loop ----------
__global__ __launch_bounds__(256) void gemm_out(const unsigned short* __restrict__ A,
                                                const unsigned short* __restrict__ Bw,
                                                const float* __restrict__ bias,
                                                float* __restrict__ Cout) {
    __shared__ __align__(16) char smem_raw[32768];
    const int tid = threadIdx.x;
    const int lane = tid & 63, w = tid >> 6;
    const int wr = w >> 1, wc = w & 1, lm = lane & 15, lg = lane >> 4;
    const int row0 = blockIdx.y * 128, col0 = blockIdx.x * 128;

    f32x4 acc[4][4];
#pragma unroll
    for (int m = 0; m < 4; ++m)
#pragma unroll
        for (int n = 0; n < 4; ++n) acc[m][n] = (f32x4){0.f, 0.f, 0.f, 0.f};

    auto As = [&](int buf) { return (short*)(smem_raw + buf * 16384); };
    auto Bs = [&](int buf) { return (short*)(smem_raw + buf * 16384 + 8192); };

    const size_t ldb = 2048;
    auto stage = [&](int kt, int buf) {
#pragma unroll
        for (int i = 0; i < 2; ++i) {
            int c = tid + 256 * i;
            int r = c >> 2, gp = c & 3;
            int gs = gp ^ ((r >> 1) & 3);
            gload_lds16((const char*)A  + (size_t)(row0 + r) * ldb + (size_t)kt * 64 + gs * 16, As(buf) + c * 8);
            gload_lds16((const char*)Bw + (size_t)(col0 + r) * ldb + (size_t)kt * 64 + gs * 16, Bs(buf) + c * 8);
        }
    };

    stage(0, 0);
    __syncthreads();
    int cur = 0;
    const int swz = (lm >> 1) & 3;
    for (int kt = 0; kt < 32; ++kt) {
        if (kt + 1 < 32) stage(kt + 1, cur ^ 1);
        bf16x8 af[4], bfr[4];
        const short* as = As(cur);
        const short* bs = Bs(cur);
#pragma unroll
        for (int m = 0; m < 4; ++m) af[m]  = *(const bf16x8*)&as[(wr * 64 + m * 16 + lm) * 32 + ((lg ^ swz) << 3)];
#pragma unroll
        for (int n = 0; n < 4; ++n) bfr[n] = *(const bf16x8*)&bs[(wc * 64 + n * 16 + lm) * 32 + ((lg ^ swz) << 3)];
#pragma unroll
        for (int m = 0; m < 4; ++m)
#pragma unroll
            for (int n = 0; n < 4; ++n) acc[m][n] = MFMA16(af[m], bfr[n], acc[m][n]);
        __syncthreads();
        cur ^= 1;
    }

#pragma unroll
    for (int m = 0; m < 4; ++m) {
        int row = row0 + wr * 64 + m * 16 + lg * 4;
#pragma unroll
        for (int n = 0; n < 4; ++n) {
            int col = col0 + wc * 64 + n * 16 + lm;
            float bv = bias[col];
#pragma unroll
            for (int r = 0; r < 4; ++r)
                Cout[(size_t)(row + r) * DIM + col] = acc[m][n][r] + bv;
        }
    }
}

// ---------- sliding-window flash attention (unchanged from R2) ----------
__global__ __launch_bounds__(256) void attn(const unsigned short* __restrict__ qb,
                                            const unsigned short* __restrict__ kb,
                                            const unsigned short* __restrict__ vt,
                                            unsigned short* __restrict__ ao) {
    const int p = blockIdx.x;
    const int L = (p & 7) * 128 + (p >> 3);
    const int qblk = L & 31, bh = L >> 5;
    const int b = bh >> 4, h = bh & 15;
    const int tid = threadIdx.x, w = tid >> 6, lane = tid & 63;
    const int lm = lane & 15, lg = lane >> 4;
    const unsigned short* Qb = qb + (size_t)bh * S_LEN * 64;
    const unsigned short* Kb = kb + (size_t)bh * S_LEN * 64;
    const unsigned short* Vt = vt + (size_t)bh * 64 * S_LEN;
    const int q0 = qblk * 64 + w * 16;

    __shared__ short Ks[2][64 * 64];
    __shared__ short Vs[2][64 * 64];
    __shared__ short Plds[4][16 * 64];
    short* Pw = Plds[w];

    bf16x8 aq0 = *(const bf16x8*)&Qb[(q0 + lm) * 64 + lg * 8];
    bf16x8 aq1 = *(const bf16x8*)&Qb[(q0 + lm) * 64 + lg * 8 + 32];

    f32x4 o[4];
#pragma unroll
    for (int n = 0; n < 4; ++n) o[n] = (f32x4){0.f, 0.f, 0.f, 0.f};
    float lsum = 0.f;

    const int qq = q0 + lm;
    const int t0 = qblk >= 8 ? qblk - 8 : 0;

    auto stage = [&](int kt, int buf) {
#pragma unroll
        for (int i = 0; i < 2; ++i) {
            int c = tid + 256 * i;
            int r = c >> 3, g = (c & 7) ^ (r & 7);
            gload_lds16(Kb + (size_t)(kt * 64 + r) * 64 + g * 8, &Ks[buf][c * 8]);
            gload_lds16(Vt + (size_t)r * S_LEN + kt * 64 + g * 8, &Vs[buf][c * 8]);
        }
    };

    stage(t0, 0);
    __syncthreads();
    int cur = 0;
    for (int kt = t0; kt <= qblk; ++kt) {
        if (kt < qblk) stage(kt + 1, cur ^ 1);
        const int kbase = kt * 64;
        const int sw = lm & 7;
        f32x4 sT[4];
#pragma unroll
        for (int n = 0; n < 4; ++n) {
            int rl = n * 16 + lm;
            bf16x8 bk0 = *(const bf16x8*)&Ks[cur][rl * 64 + ((lg ^ sw) << 3)];
            bf16x8 bk1 = *(const bf16x8*)&Ks[cur][rl * 64 + (((lg + 4) ^ sw) << 3)];
            f32x4 z = (f32x4){0.f, 0.f, 0.f, 0.f};
            z = MFMA16(bk0, aq0, z);
            sT[n] = MFMA16(bk1, aq1, z);
        }
#pragma unroll
        for (int n = 0; n < 4; ++n) {
            int kk0 = kbase + n * 16 + lg * 4;
#pragma unroll
            for (int r = 0; r < 4; ++r) {
                int d = qq - (kk0 + r);
                float sv = ((unsigned)d < (unsigned)WIN) ? sT[n][r] : -1e30f;
                float pv = __expf(sv);
                sT[n][r] = pv;
                lsum += pv;
            }
            uint2 pk;
            pk.x = pack2bf(sT[n][0], sT[n][1]);
            pk.y = pack2bf(sT[n][2], sT[n][3]);
            *(uint2*)&Pw[lm * 64 + ((((2 * n + (lg >> 1)) ^ sw) << 3) + ((lg & 1) << 2))] = pk;
        }
        bf16x8 ap0 = *(const bf16x8*)&Pw[lm * 64 + ((lg ^ sw) << 3)];
        bf16x8 ap1 = *(const bf16x8*)&Pw[lm * 64 + (((lg + 4) ^ sw) << 3)];
#pragma unroll
        for (int n = 0; n < 4; ++n) {
            int rl = n * 16 + lm;
            bf16x8 bv0 = *(const bf16x8*)&Vs[cur][rl * 64 + ((lg ^ sw) << 3)];
            bf16x8 bv1 = *(const bf16x8*)&Vs[cur][rl * 64 + (((lg + 4) ^ sw) << 3)];
            o[n] = MFMA16(ap0, bv0, o[n]);
            o[n] = MFMA16(ap1, bv1, o[n]);
        }
        __syncthreads();
        cur ^= 1;
    }
    lsum += __shfl_xor(lsum, 16, 64);
    lsum += __shfl_xor(lsum, 32, 64);
    float linv = 1.f / lsum;
    float lrow[4];
#pragma unroll
    for (int r = 0; r < 4; ++r) lrow[r] = __shfl(linv, lg * 4 + r, 64);
#pragma unroll
    for (int n = 0; n < 4; ++n)
#pragma unroll
        for (int r = 0; r < 4; ++r) {
            int row = b * S_LEN + q0 + lg * 4 + r;
            int col = h * 64 + n * 16 + lm;
            ao[(size_t)row * DIM + col] = f2bf(o[n][r] * lrow[r]);
        }
}

// ---------- launch ----------
extern "C" void kernel_launch(void* const* d_in, const int* in_sizes, int n_in,
                              void* d_out, int out_size, void* d_ws, size_t ws_size,
                              hipStream_t stream) {
    const float* x      = (const float*)d_in[0];
    const float* qkv_w  = (const float*)d_in[1];
    const float* qkv_b  = (const float*)d_in[2];
    const float* out_w  = (const float*)d_in[3];
    const float* out_b  = (const float*)d_in[4];
    (void)in_sizes; (void)n_in; (void)out_size; (void)ws_size;

    char* ws = (char*)d_ws;
    float*          cosT = (float*)(ws + 0);
    float*          sinT = (float*)(ws + 262144);
    unsigned short* xb   = (unsigned short*)(ws + 524288);
    unsigned short* wqb  = (unsigned short*)(ws + 8912896);
    unsigned short* owb  = (unsigned short*)(ws + 15204352);
    unsigned short* qbuf = (unsigned short*)(ws + 17301504);
    unsigned short* kbuf = (unsigned short*)(ws + 25690112);
    unsigned short* vtb  = (unsigned short*)(ws + 34078720);
    unsigned short* aob  = (unsigned short*)(ws + 42467328);

    prep<<<8448, 256, 0, stream>>>(cosT, sinT, x, xb, qkv_w, wqb, out_w, owb);

    gemm_qkv_fused<<<dim3(24, 32), 256, 0, stream>>>(xb, wqb, qkv_b, cosT, sinT,
                                                     qbuf, kbuf, vtb);

    attn<<<1024, 256, 0, stream>>>(qbuf, kbuf, vtb, aob);

    gemm_out<<<dim3(8, 32), 256, 0, stream>>>(aob, owb, out_b, (float*)d_out);
}